// Round 10
// baseline (580.689 us; speedup 1.0000x reference)
//
#include <hip/hip_runtime.h>

#define N_NODES 50000
#define N_REL 16
#define D 128
#define N_SEG (N_NODES * N_REL)  // 800000

typedef short bf16x8 __attribute__((ext_vector_type(8)));
typedef float f32x4 __attribute__((ext_vector_type(4)));
typedef unsigned short u16;
typedef unsigned int u32;

__device__ __forceinline__ u16 f32_to_bf16(float f) {
  u32 u = __builtin_bit_cast(u32, f);
  u32 r = (u + 0x7FFFu + ((u >> 16) & 1u)) >> 16;
  return (u16)r;
}
__device__ __forceinline__ float bf16_to_f32(u16 h) {
  u32 u = ((u32)h) << 16;
  return __builtin_bit_cast(float, u);
}

// ---------------- zero (uint4 grid-stride) ----------------
__global__ __launch_bounds__(256) void k_zero4(uint4* __restrict__ p, long long n4) {
  long long i = (long long)blockIdx.x * blockDim.x + threadIdx.x;
  long long stride = (long long)gridDim.x * blockDim.x;
  uint4 z; z.x = z.y = z.z = z.w = 0u;
  for (; i < n4; i += stride) p[i] = z;
}

// ---------------- f32 -> bf16 convert (x4 per thread) ----------------
__global__ __launch_bounds__(256) void k_cvt(const float* __restrict__ in,
                                             u16* __restrict__ out, long long n4) {
  long long i = (long long)blockIdx.x * blockDim.x + threadIdx.x;
  if (i >= n4) return;
  float4 v = ((const float4*)in)[i];
  u32 p0 = (u32)f32_to_bf16(v.x) | ((u32)f32_to_bf16(v.y) << 16);
  u32 p1 = (u32)f32_to_bf16(v.z) | ((u32)f32_to_bf16(v.w) << 16);
  ((u32*)out)[i * 2] = p0;
  ((u32*)out)[i * 2 + 1] = p1;
}

// ---------------- per-(dst,rel) edge counts ----------------
__global__ __launch_bounds__(256) void k_count(const int* __restrict__ dst,
                                               const int* __restrict__ rel,
                                               int* __restrict__ cnt, int E) {
  int e = blockIdx.x * blockDim.x + threadIdx.x;
  if (e < E) atomicAdd(&cnt[dst[e] * N_REL + rel[e]], 1);
}

// ---------------- scan: per-block sums ----------------
__global__ __launch_bounds__(256) void k_bsum(const int* __restrict__ cnt,
                                              int* __restrict__ bsum, int n) {
  __shared__ int sm[256];
  int i = blockIdx.x * 256 + threadIdx.x;
  int v = (i < n) ? cnt[i] : 0;
  sm[threadIdx.x] = v;
  __syncthreads();
  for (int s = 128; s > 0; s >>= 1) {
    if (threadIdx.x < s) sm[threadIdx.x] += sm[threadIdx.x + s];
    __syncthreads();
  }
  if (threadIdx.x == 0) bsum[blockIdx.x] = sm[0];
}

// ---------------- scan: single-block exclusive scan of block sums ----------------
__global__ __launch_bounds__(1024) void k_bscan(int* __restrict__ bsum, int nb) {
  __shared__ int sm[1024];
  __shared__ int carry;
  if (threadIdx.x == 0) carry = 0;
  __syncthreads();
  int niter = (nb + 1023) / 1024;
  for (int it = 0; it < niter; ++it) {
    int i = it * 1024 + threadIdx.x;
    int v = (i < nb) ? bsum[i] : 0;
    sm[threadIdx.x] = v;
    __syncthreads();
    for (int s = 1; s < 1024; s <<= 1) {
      int t = (threadIdx.x >= s) ? sm[threadIdx.x - s] : 0;
      __syncthreads();
      sm[threadIdx.x] += t;
      __syncthreads();
    }
    int incl = sm[threadIdx.x];
    int c = carry;
    __syncthreads();
    if (i < nb) bsum[i] = c + incl - v;
    if (threadIdx.x == 1023) carry = c + sm[1023];
    __syncthreads();
  }
}

// ---------------- scan: per-element exclusive offsets ----------------
__global__ __launch_bounds__(256) void k_off(const int* __restrict__ cnt,
                                             const int* __restrict__ bsum,
                                             int* __restrict__ off, int n) {
  __shared__ int sm[256];
  int i = blockIdx.x * 256 + threadIdx.x;
  int v = (i < n) ? cnt[i] : 0;
  sm[threadIdx.x] = v;
  __syncthreads();
  for (int s = 1; s < 256; s <<= 1) {
    int t = (threadIdx.x >= s) ? sm[threadIdx.x - s] : 0;
    __syncthreads();
    sm[threadIdx.x] += t;
    __syncthreads();
  }
  int excl = sm[threadIdx.x] - v + bsum[blockIdx.x];
  if (i < n) off[i] = excl;
  if (i == n - 1) off[n] = excl + v;
}

// ---------------- CSR fill (countdown — cnt is dead after k_off) ----------------
__global__ __launch_bounds__(256) void k_fill(const int* __restrict__ src,
                                              const int* __restrict__ dst,
                                              const int* __restrict__ rel,
                                              const int* __restrict__ off,
                                              int* __restrict__ cnt,
                                              int* __restrict__ bucket, int E) {
  int e = blockIdx.x * blockDim.x + threadIdx.x;
  if (e >= E) return;
  int seg = dst[e] * N_REL + rel[e];
  int old = atomicSub(&cnt[seg], 1);          // old in [1, cnt]
  bucket[off[seg] + old - 1] = src[e];
}

// ---------------- weight -> MFMA-fragment-linear bf16 ----------------
// Wf[(kb*8+t)*512 + lane*8 + j] = Bmat[k = kb*32 + (lane>>4)*8 + j][h = t*16 + (lane&15)]
// Bmat[k][h] = W[k>>7][k&127][h]  (root: nkb=4 -> k<128 -> r=0)
__global__ __launch_bounds__(256) void k_wfrag(const float* __restrict__ W,
                                               u16* __restrict__ Wf, int nkb) {
  int tid = blockIdx.x * blockDim.x + threadIdx.x;
  int total = nkb * 8 * 64;
  if (tid >= total) return;
  int lane = tid & 63;
  int t = (tid >> 6) & 7;
  int kb = tid >> 9;
  int h = t * 16 + (lane & 15);
  int kbase = kb * 32 + ((lane >> 4) << 3);
  bf16x8 frag;
#pragma unroll
  for (int j = 0; j < 8; ++j) {
    int k = kbase + j;
    frag[j] = (short)f32_to_bf16(W[(size_t)(k >> 7) * (D * D) + (size_t)(k & 127) * D + h]);
  }
  *(bf16x8*)(Wf + (size_t)tid * 8) = frag;   // tid*8 u16 = 16B aligned
}

// ---------------- fully fused RGCN layer, relation-split x4, MLP-unrolled gather ----------
// One 16-node M-tile per BLOCK; 4 waves own 4 relations each (+ 1 kb-quarter of the
// root term). Gather-mean goes straight into A-fragment registers with a 4-edge
// unrolled loop (4 bucket loads then 16 row loads in flight before any accumulate)
// to break the serial bucket->row latency chain. LDS reduce; fused bias(+ReLU)+store.
template <int L>  // L=1: bf16 out + ReLU; L=2: f32 out
__global__ __launch_bounds__(256) void k_layer(const int* __restrict__ off,
                                               const int* __restrict__ bucket,
                                               const u16* __restrict__ x,    // [N,128] bf16
                                               const u16* __restrict__ Wf,   // 64 kb frag-linear
                                               const u16* __restrict__ Rf,   // 4 kb frag-linear
                                               const float* __restrict__ bias,
                                               u16* __restrict__ outb,
                                               float* __restrict__ outf) {
  __shared__ f32x4 red[4][8][64];      // 32 KB
  int w = threadIdx.x >> 6;            // wave 0..3
  int lane = threadIdx.x & 63;
  int node0 = blockIdx.x << 4;         // 50000 = 3125*16, exact grid
  int m = lane & 15;
  int q = lane >> 4;
  int node = node0 + m;                // A-row this lane serves

  // hoist the wave's 5 offsets (segments node*16 + w*4 .. +4) out of the chain
  int ob[5];
  {
    const int* op = off + (node << 4) + (w << 2);
#pragma unroll
    for (int j = 0; j < 5; ++j) ob[j] = op[j];
  }

  f32x4 acc[8];
#pragma unroll
  for (int t = 0; t < 8; ++t)
#pragma unroll
    for (int i = 0; i < 4; ++i) acc[t][i] = 0.0f;

  // ---- root term: this wave does kb = w ----
  {
    bf16x8 a = *(const bf16x8*)(x + ((size_t)node << 7) + w * 32 + (q << 3));
    const u16* bp = Rf + ((size_t)w << 12) + ((size_t)lane << 3);
#pragma unroll
    for (int t = 0; t < 8; ++t) {
      bf16x8 b = *(const bf16x8*)(bp + t * 512);
      acc[t] = __builtin_amdgcn_mfma_f32_16x16x32_bf16(a, b, acc[t], 0, 0, 0);
    }
  }

  // ---- 4 relations per wave: gather-mean into A-frag regs, MFMA vs W_r ----
  for (int rr = 0; rr < 4; ++rr) {
    int r = (w << 2) + rr;
    int o0 = ob[rr];
    int o1 = ob[rr + 1];

    float a0[8], a1[8], a2[8], a3[8];
#pragma unroll
    for (int j = 0; j < 8; ++j) { a0[j] = 0.f; a1[j] = 0.f; a2[j] = 0.f; a3[j] = 0.f; }

    int i = o0;
    // 4-edge unrolled main: 4 independent bucket loads, then 16 row loads in
    // flight before any accumulate. Accumulation order per edge unchanged.
    for (; i + 4 <= o1; i += 4) {
      int s0 = bucket[i];
      int s1 = bucket[i + 1];
      int s2 = bucket[i + 2];
      int s3 = bucket[i + 3];
      const u16* p0 = x + ((size_t)s0 << 7) + (q << 3);
      const u16* p1 = x + ((size_t)s1 << 7) + (q << 3);
      const u16* p2 = x + ((size_t)s2 << 7) + (q << 3);
      const u16* p3 = x + ((size_t)s3 << 7) + (q << 3);
      bf16x8 v[4][4];
#pragma unroll
      for (int kb = 0; kb < 4; ++kb) v[0][kb] = *(const bf16x8*)(p0 + kb * 32);
#pragma unroll
      for (int kb = 0; kb < 4; ++kb) v[1][kb] = *(const bf16x8*)(p1 + kb * 32);
#pragma unroll
      for (int kb = 0; kb < 4; ++kb) v[2][kb] = *(const bf16x8*)(p2 + kb * 32);
#pragma unroll
      for (int kb = 0; kb < 4; ++kb) v[3][kb] = *(const bf16x8*)(p3 + kb * 32);
#pragma unroll
      for (int e = 0; e < 4; ++e) {
#pragma unroll
        for (int j = 0; j < 8; ++j) {
          a0[j] += bf16_to_f32((u16)v[e][0][j]);
          a1[j] += bf16_to_f32((u16)v[e][1][j]);
          a2[j] += bf16_to_f32((u16)v[e][2][j]);
          a3[j] += bf16_to_f32((u16)v[e][3][j]);
        }
      }
    }
    // tail
    for (; i < o1; ++i) {
      int s = bucket[i];
      const u16* xs = x + ((size_t)s << 7) + (q << 3);
      bf16x8 v0 = *(const bf16x8*)(xs);
      bf16x8 v1 = *(const bf16x8*)(xs + 32);
      bf16x8 v2 = *(const bf16x8*)(xs + 64);
      bf16x8 v3 = *(const bf16x8*)(xs + 96);
#pragma unroll
      for (int j = 0; j < 8; ++j) {
        a0[j] += bf16_to_f32((u16)v0[j]);
        a1[j] += bf16_to_f32((u16)v1[j]);
        a2[j] += bf16_to_f32((u16)v2[j]);
        a3[j] += bf16_to_f32((u16)v3[j]);
      }
    }

    float sc = (o1 > o0) ? 1.0f / (float)(o1 - o0) : 0.0f;
    bf16x8 f0, f1, f2, f3;
#pragma unroll
    for (int j = 0; j < 8; ++j) {
      f0[j] = (short)f32_to_bf16(a0[j] * sc);
      f1[j] = (short)f32_to_bf16(a1[j] * sc);
      f2[j] = (short)f32_to_bf16(a2[j] * sc);
      f3[j] = (short)f32_to_bf16(a3[j] * sc);
    }

    const u16* bp = Wf + ((size_t)(r * 4) << 12) + ((size_t)lane << 3);
#pragma unroll
    for (int t = 0; t < 8; ++t) {
      bf16x8 b0 = *(const bf16x8*)(bp + t * 512);
      bf16x8 b1 = *(const bf16x8*)(bp + 4096 + t * 512);
      bf16x8 b2 = *(const bf16x8*)(bp + 8192 + t * 512);
      bf16x8 b3 = *(const bf16x8*)(bp + 12288 + t * 512);
      acc[t] = __builtin_amdgcn_mfma_f32_16x16x32_bf16(f0, b0, acc[t], 0, 0, 0);
      acc[t] = __builtin_amdgcn_mfma_f32_16x16x32_bf16(f1, b1, acc[t], 0, 0, 0);
      acc[t] = __builtin_amdgcn_mfma_f32_16x16x32_bf16(f2, b2, acc[t], 0, 0, 0);
      acc[t] = __builtin_amdgcn_mfma_f32_16x16x32_bf16(f3, b3, acc[t], 0, 0, 0);
    }
  }

  // ---- LDS reduce across the 4 waves ----
#pragma unroll
  for (int t = 0; t < 8; ++t) red[w][t][lane] = acc[t];
  __syncthreads();

  // ---- epilogue: wave w handles t = 2w, 2w+1; C layout col=m, row=q*4+reg [m89] ----
#pragma unroll
  for (int j = 0; j < 2; ++j) {
    int t = w * 2 + j;
    f32x4 s0 = red[0][t][lane];
    f32x4 s1 = red[1][t][lane];
    f32x4 s2 = red[2][t][lane];
    f32x4 s3 = red[3][t][lane];
    int h = t * 16 + m;
    float bv = bias[h];
#pragma unroll
    for (int r4 = 0; r4 < 4; ++r4) {
      int n = node0 + (q << 2) + r4;
      float v = s0[r4] + s1[r4] + s2[r4] + s3[r4] + bv;
      if (L == 1) {
        v = v > 0.0f ? v : 0.0f;
        outb[(size_t)n * D + h] = f32_to_bf16(v);
      } else {
        outf[(size_t)n * D + h] = v;
      }
    }
  }
}

extern "C" void kernel_launch(void* const* d_in, const int* in_sizes, int n_in,
                              void* d_out, int out_size, void* d_ws, size_t ws_size,
                              hipStream_t stream) {
  const int* edge_index = (const int*)d_in[0];
  const int* edge_type  = (const int*)d_in[1];
  const float* emb   = (const float*)d_in[2];
  const float* W1    = (const float*)d_in[3];
  const float* root1 = (const float*)d_in[4];
  const float* b1    = (const float*)d_in[5];
  const float* W2    = (const float*)d_in[6];
  const float* root2 = (const float*)d_in[7];
  const float* b2    = (const float*)d_in[8];
  float* out = (float*)d_out;

  int E = in_sizes[0] / 2;
  const int* src = edge_index;      // row 0
  const int* dst = edge_index + E;  // row 1
  int nblocks_seg = (N_SEG + 255) / 256;  // 3125

  char* ws = (char*)d_ws;
  size_t off_b = 0;
  auto take = [&](size_t bytes) -> char* {
    char* p = ws + off_b;
    off_b += (bytes + 255) & ~(size_t)255;
    return p;
  };
  int*   cnt    = (int*)take((size_t)N_SEG * 4);
  int*   offs   = (int*)take((size_t)(N_SEG + 1) * 4);
  int*   bsum   = (int*)take((size_t)nblocks_seg * 4);
  int*   bucket = (int*)take((size_t)E * 4);
  u16*   embb   = (u16*)take((size_t)N_NODES * D * 2);
  u16*   x1     = (u16*)take((size_t)N_NODES * D * 2);
  u16*   Wf1    = (u16*)take((size_t)64 * 8 * 512 * 2);
  u16*   Rf1    = (u16*)take((size_t)4 * 8 * 512 * 2);
  u16*   Wf2    = (u16*)take((size_t)64 * 8 * 512 * 2);
  u16*   Rf2    = (u16*)take((size_t)4 * 8 * 512 * 2);
  // total ~41 MB — fits comfortably

  int eBlocks = (E + 255) / 256;
  int layerBlocks = N_NODES / 16;   // 3125 blocks, 1 tile per block

  // --- CSR build (shared by both layers) ---
  k_zero4<<<512, 256, 0, stream>>>((uint4*)cnt, (long long)N_SEG * 4 / 16);
  k_count<<<eBlocks, 256, 0, stream>>>(dst, edge_type, cnt, E);
  k_bsum<<<nblocks_seg, 256, 0, stream>>>(cnt, bsum, N_SEG);
  k_bscan<<<1, 1024, 0, stream>>>(bsum, nblocks_seg);
  k_off<<<nblocks_seg, 256, 0, stream>>>(cnt, bsum, offs, N_SEG);
  k_fill<<<eBlocks, 256, 0, stream>>>(src, dst, edge_type, offs, cnt, bucket, E);

  // --- weight prep ---
  k_cvt<<<((N_NODES * D / 4) + 255) / 256, 256, 0, stream>>>(emb, embb,
                                                             (long long)N_NODES * D / 4);
  k_wfrag<<<(64 * 8 * 64 + 255) / 256, 256, 0, stream>>>(W1, Wf1, 64);
  k_wfrag<<<(4 * 8 * 64 + 255) / 256, 256, 0, stream>>>(root1, Rf1, 4);
  k_wfrag<<<(64 * 8 * 64 + 255) / 256, 256, 0, stream>>>(W2, Wf2, 64);
  k_wfrag<<<(4 * 8 * 64 + 255) / 256, 256, 0, stream>>>(root2, Rf2, 4);

  // --- two fused layers ---
  k_layer<1><<<layerBlocks, 256, 0, stream>>>(offs, bucket, embb, Wf1, Rf1, b1,
                                              x1, nullptr);
  k_layer<2><<<layerBlocks, 256, 0, stream>>>(offs, bucket, x1, Wf2, Rf2, b2,
                                              nullptr, out);
}